// Round 13
// baseline (506.076 us; speedup 1.0000x reference)
//
#include <hip/hip_runtime.h>
#include <cstdint>

#define B_ 4
#define C_ 256
#define HW_ 4096
#define CPG_ 8
#define M_TOT 16384
#define SCALE 0.0625f
#define LOG2E 1.44269504088896f
#define FLASH_LDS 135168

typedef __attribute__((ext_vector_type(4))) float f32x4;
typedef __attribute__((ext_vector_type(16))) float f32x16;
typedef __attribute__((ext_vector_type(8))) unsigned short u16x8;
typedef __attribute__((ext_vector_type(4))) unsigned short u16x4;
typedef __attribute__((ext_vector_type(4))) unsigned int u32x4;
typedef __attribute__((ext_vector_type(8))) __bf16 bf16x8;

static __device__ __forceinline__ unsigned short f2bf(float f) {
  unsigned int u = __builtin_bit_cast(unsigned int, f);
  u += 0x7fffu + ((u >> 16) & 1u);
  return (unsigned short)(u >> 16);
}
static __device__ __forceinline__ float bf2f(unsigned short s) {
  return __builtin_bit_cast(float, ((unsigned int)s) << 16);
}
static __device__ __forceinline__ bf16x8 ldbf8(const unsigned short* p) {
  return __builtin_bit_cast(bf16x8, *(const u16x8*)p);
}
static __device__ __forceinline__ bf16x8 cvt8(const float* p) {
  f32x4 a = *(const f32x4*)p;
  f32x4 b = *(const f32x4*)(p + 4);
  u16x8 r;
  r[0] = f2bf(a[0]); r[1] = f2bf(a[1]); r[2] = f2bf(a[2]); r[3] = f2bf(a[3]);
  r[4] = f2bf(b[0]); r[5] = f2bf(b[1]); r[6] = f2bf(b[2]); r[7] = f2bf(b[3]);
  return __builtin_bit_cast(bf16x8, r);
}
// async global->LDS, 16B per lane; LDS dest wave-uniform base, HW adds lane*16
static __device__ __forceinline__ void gload16(const void* g, void* l) {
  __builtin_amdgcn_global_load_lds(
      (const __attribute__((address_space(1))) unsigned int*)g,
      (__attribute__((address_space(3))) unsigned int*)l, 16, 0, 0);
}
// packed f32->bf16 pair (RTNE), no builtin on gfx950
static __device__ __forceinline__ unsigned cvtpk(float lo, float hi) {
  unsigned r;
  asm("v_cvt_pk_bf16_f32 %0, %1, %2" : "=v"(r) : "v"(lo), "v"(hi));
  return r;
}

// ---------------- GroupNorm stats: per-(b,g) coefficients ----------------
__global__ __launch_bounds__(256) void gn_stats(const float* __restrict__ x,
    const float* __restrict__ gamma, const float* __restrict__ beta,
    float* __restrict__ gnab) {
  int bg = blockIdx.x;
  int b = bg >> 5, g = bg & 31;
  const float* xp = x + ((size_t)(b * C_ + g * CPG_)) * HW_;
  float s = 0.f, ss = 0.f;
  for (int i = threadIdx.x; i < CPG_ * HW_; i += 256) {
    float v = xp[i]; s += v; ss += v * v;
  }
#pragma unroll
  for (int m = 32; m; m >>= 1) { s += __shfl_xor(s, m); ss += __shfl_xor(ss, m); }
  __shared__ float red[8];
  if ((threadIdx.x & 63) == 0) { red[threadIdx.x >> 6] = s; red[4 + (threadIdx.x >> 6)] = ss; }
  __syncthreads();
  if (threadIdx.x < CPG_) {
    float S = red[0] + red[1] + red[2] + red[3];
    float SS = red[4] + red[5] + red[6] + red[7];
    float mean = S * (1.f / 32768.f);
    float var = SS * (1.f / 32768.f) - mean * mean;
    float rs = rsqrtf(var + 1e-6f);
    int c = g * CPG_ + threadIdx.x;
    float gm = gamma[c];
    gnab[b * C_ + c] = gm * rs;
    gnab[1024 + b * C_ + c] = beta[c] - mean * gm * rs;
  }
}

// ---------------- GroupNorm apply -> t bf16 [b][s][c], coalesced writes ------
__global__ __launch_bounds__(256) void gn_apply(const float* __restrict__ x,
    const float* __restrict__ gnab, unsigned short* __restrict__ t) {
  __shared__ unsigned short T[64][264];
  int blk = blockIdx.x;
  int b = blk >> 6;
  int sp0 = (blk & 63) * 64;
  int tid = threadIdx.x;
  int l = tid & 63, w = tid >> 6;
  const float* xb = x + (size_t)b * C_ * HW_;
  const float* ga = gnab + b * C_;
  const float* gb = gnab + 1024 + b * C_;
  for (int c0 = w * 64; c0 < w * 64 + 64; c0 += 8) {
    u16x8 o;
#pragma unroll
    for (int j = 0; j < 8; ++j) {
      int c = c0 + j;
      float v = xb[(size_t)c * HW_ + sp0 + l];
      o[j] = f2bf(v * ga[c] + gb[c]);
    }
    *(u16x8*)&T[l][c0] = o;
  }
  __syncthreads();
  for (int e = tid; e < 64 * 32; e += 256) {
    int row = e >> 5, c8 = (e & 31) * 8;
    *(u16x8*)(t + ((size_t)(b * HW_ + sp0 + row)) * C_ + c8) =
        *(const u16x8*)&T[row][c8];
  }
}

// ---------------- u = sigmoid(t . wu + bu), one wave per token ----------------
__global__ __launch_bounds__(256) void u_kernel(const unsigned short* __restrict__ t,
    const float* __restrict__ wu, const float* __restrict__ bu,
    float* __restrict__ uout) {
  int w = threadIdx.x >> 6, l = threadIdx.x & 63;
  int tok = blockIdx.x * 4 + w;
  u16x4 tv = *(const u16x4*)(t + (size_t)tok * C_ + l * 4);
  f32x4 wv4 = *(const f32x4*)(wu + l * 4);
  float d = bf2f(tv[0]) * wv4[0] + bf2f(tv[1]) * wv4[1] +
            bf2f(tv[2]) * wv4[2] + bf2f(tv[3]) * wv4[3];
#pragma unroll
  for (int m = 32; m; m >>= 1) d += __shfl_xor(d, m);
  if (l == 0) uout[tok] = 1.f / (1.f + __expf(-(d + bu[0])));
}

// ---------------- fused QKV projection: A in regs, 3 sequential W stages -----
// K path folds SCALE*u[row]*LOG2E so flash softmax runs in exp2 domain.
__global__ __launch_bounds__(256, 2) void qkv_kernel(const unsigned short* __restrict__ t,
    const float* __restrict__ wq, const float* __restrict__ wk, const float* __restrict__ wv,
    const float* __restrict__ bq, const float* __restrict__ bk, const float* __restrict__ bv,
    const float* __restrict__ uu,
    unsigned short* __restrict__ q, unsigned short* __restrict__ k,
    unsigned short* __restrict__ vt) {
  int mblk = blockIdx.x, nblk = blockIdx.y;
  int n0 = nblk * 64;
  __shared__ unsigned short WL[64][264];
  __shared__ float lds[64][65];
  int tid = threadIdx.x;
  int wid = tid >> 6, l = tid & 63;
  int lr = l & 15, lg = l >> 4;
  int row = mblk * 64 + wid * 16 + lr;
  bf16x8 af[8];
  const unsigned short* ap = t + (size_t)row * C_ + lg * 8;
#pragma unroll
  for (int kc = 0; kc < 8; ++kc) af[kc] = ldbf8(ap + kc * 32);
  f32x4 u4 = *(const f32x4*)(uu + mblk * 64 + wid * 16 + lg * 4);

#pragma unroll 1
  for (int w = 0; w < 3; ++w) {
    const float* W = w == 0 ? wq : (w == 1 ? wk : wv);
    const float* bias = w == 0 ? bq : (w == 1 ? bk : bv);
    if (w) __syncthreads();
#pragma unroll
    for (int p = 0; p < 8; ++p) {
      int rw = p * 8 + (tid >> 5);
      int kc0 = (tid & 31) * 8;
      *(bf16x8*)&WL[rw][kc0] = cvt8(W + (size_t)(n0 + rw) * C_ + kc0);
    }
    __syncthreads();
    f32x4 acc[4] = {};
#pragma unroll
    for (int kc = 0; kc < 8; ++kc)
#pragma unroll
      for (int j = 0; j < 4; ++j) {
        bf16x8 bb = ldbf8(&WL[j * 16 + lr][kc * 32 + lg * 8]);
        acc[j] = __builtin_amdgcn_mfma_f32_16x16x32_bf16(af[kc], bb, acc[j], 0, 0, 0);
      }
    if (w < 2) {
      unsigned short* dst = w ? k : q;
      float su[4] = {1.f, 1.f, 1.f, 1.f};
      if (w == 1) {
        su[0] = SCALE * LOG2E * u4[0]; su[1] = SCALE * LOG2E * u4[1];
        su[2] = SCALE * LOG2E * u4[2]; su[3] = SCALE * LOG2E * u4[3];
      }
#pragma unroll
      for (int j = 0; j < 4; ++j) {
        int col = n0 + j * 16 + lr;
        float bv_ = bias[col];
#pragma unroll
        for (int r = 0; r < 4; ++r)
          dst[(size_t)(mblk * 64 + wid * 16 + lg * 4 + r) * C_ + col] =
              f2bf((acc[j][r] + bv_) * su[r]);
      }
    } else {
#pragma unroll
      for (int j = 0; j < 4; ++j) {
        float bv_ = bias[n0 + j * 16 + lr];
#pragma unroll
        for (int r = 0; r < 4; ++r)
          lds[wid * 16 + lg * 4 + r][j * 16 + lr] = acc[j][r] + bv_;
      }
      __syncthreads();
      int bb_ = (mblk * 64) >> 12;
      int s0 = (mblk * 64) & 4095;
      int ss = tid & 63, cc0 = tid >> 6;
      for (int cc = cc0; cc < 64; cc += 4)
        vt[((size_t)(bb_ * C_ + n0 + cc)) * HW_ + s0 + ss] = f2bf(lds[ss][cc]);
    }
  }
}

// ---------------- flash attention v13: v12 structure, FIXED launch bounds ----
// 128 blocks x 768 threads, __launch_bounds__(768, 1): 1 block/CU, 3 waves/
// SIMD, full register budget (v12's (768,3) capped VGPR at 84 -> oa spilled
// to scratch: WRITE_SIZE 3x, FETCH 2x, MfmaUtil 6%). Waves 0-7 compute,
// waves 8-11 stage. Staging bytes per unit work halved vs v11.
__global__ __launch_bounds__(768, 1) void flash_kernel(const unsigned short* __restrict__ q,
    const unsigned short* __restrict__ k, const unsigned short* __restrict__ vt,
    unsigned short* __restrict__ o) {
  extern __shared__ char smem[];
  // K(buf,h) @ buf*32768 + h*16384   (64KB)
  // V(buf,h) @ 65536 + buf*32768 + h*16384 (64KB)
  // cmb_m @131072, cmb_l @132096, facw @133120, scrL @134144 (8 waves x 32)
  // epilogue overlay: Oacc f32[128][256] @ 0 (128KB)
  float* cmb_m = (float*)(smem + 131072);
  float* cmb_l = (float*)(smem + 132096);
  float* facw  = (float*)(smem + 133120);
  float* scrL  = (float*)(smem + 134144);
  float* Oacc  = (float*)smem;

  int blk = blockIdx.x;
  int b = blk >> 5;
  int qrow0 = (blk & 31) * 128;
  int tid = threadIdx.x;
  int wid = tid >> 6, l = tid & 63;
  int l5 = l & 31, hi = l >> 5;

  const unsigned short* kb = k + (size_t)b * HW_ * C_;
  const unsigned short* vb = vt + (size_t)b * C_ * HW_;

  float mrow = -1e30f, lrow = 0.f, l_all = 0.f;
  f32x16 oa[8];
  int h = wid >> 2, qs = wid & 3;          // compute-wave roles (wid<8)

  if (wid >= 8) {
    // ================= stager waves =================
    int role = wid - 8;
    int sh = role & 1;
    bool isK = role < 2;
    int w_ = l >> 2;
    int w0_ = w_ & 1, w1_ = (w_ >> 1) & 1, w2_ = (w_ >> 2) & 1, w3_ = (w_ >> 3) & 1;
    int koffb = (l & 3) * 8;
#define STG(IT, BUFN)                                                           \
    {                                                                           \
      int key0n = sh * 2048 + (IT) * 32;                                        \
      if (isK) {                                                                \
        _Pragma("unroll")                                                       \
        for (int j = 0; j < 16; ++j) {                                          \
          int key = j * 2 + hi;                                                 \
          const unsigned short* g =                                             \
              kb + (size_t)(key0n + key) * C_ + ((l5 * 8) ^ (key * 8));         \
          gload16(g, smem + (BUFN) * 32768 + sh * 16384 + j * 1024);            \
        }                                                                       \
      } else {                                                                  \
        _Pragma("unroll")                                                       \
        for (int j = 0; j < 16; ++j) {                                          \
          int j0 = j & 1;                                                       \
          int ch = (j << 4) | (w3_ << 3) | ((w2_ ^ j0) << 2) |                  \
                   ((w1_ ^ w3_) << 1) | (w0_ ^ w2_ ^ j0);                       \
          int ke = koffb ^ ((ch & 3) << 3);                                     \
          const unsigned short* g = vb + (size_t)ch * HW_ + key0n + ke;         \
          gload16(g, smem + 65536 + (BUFN) * 32768 + sh * 16384 + j * 1024);    \
        }                                                                       \
      }                                                                         \
    }
    STG(0, 0);
    __syncthreads();                       // barrier 1
    for (int it = 0; it < 64; ++it) {
      if (it + 1 < 64) STG(it + 1, (it + 1) & 1);
      __syncthreads();                     // barriers 2..65
    }
#undef STG
  } else {
    // ================= compute waves =================
    bf16x8 qreg[16];
    {
      const unsigned short* qp =
          q + ((size_t)b * HW_ + qrow0 + qs * 32 + l5) * C_ + hi * 8;
#pragma unroll
      for (int cc = 0; cc < 16; ++cc) qreg[cc] = ldbf8(qp + cc * 16);
    }
#pragma unroll
    for (int ct = 0; ct < 8; ++ct)
#pragma unroll
      for (int r = 0; r < 16; ++r) oa[ct][r] = 0.f;
    __syncthreads();                       // barrier 1

    int kx = l5 << 4;
    int vbase = (l5 * 64) ^ ((l5 >> 2) << 6);
    int ko0 = (hi * 16) ^ ((l & 3) << 4);
    int ko1 = (32 + hi * 16) ^ ((l & 3) << 4);

    for (int it = 0; it < 64; ++it) {
      int buf = it & 1;
      // ---- QK^T swapped: S^T[key][q] (log2 units), A=K LDS, B=Q regs ----
      const char* KB = smem + buf * 32768 + h * 16384;
      f32x16 s;
#pragma unroll
      for (int r = 0; r < 16; ++r) s[r] = 0.f;
#pragma unroll
      for (int cc = 0; cc < 16; ++cc) {
        bf16x8 kf = ldbf8((const unsigned short*)(KB + l5 * 512 +
                                                  ((cc * 32 + hi * 16) ^ kx)));
        s = __builtin_amdgcn_mfma_f32_32x32x16_bf16(kf, qreg[cc], s, 0, 0, 0);
      }
      // ---- per-lane online softmax (exp2 domain, defer-max THR=11) ----
      float a0 = fmaxf(s[0], s[1]),   a1 = fmaxf(s[2], s[3]);
      float a2 = fmaxf(s[4], s[5]),   a3 = fmaxf(s[6], s[7]);
      float a4 = fmaxf(s[8], s[9]),   a5 = fmaxf(s[10], s[11]);
      float a6 = fmaxf(s[12], s[13]), a7 = fmaxf(s[14], s[15]);
      float b0 = fmaxf(fmaxf(a0, a1), fmaxf(a2, a3));
      float b1 = fmaxf(fmaxf(a4, a5), fmaxf(a6, a7));
      float mxl = fmaxf(b0, b1);
      float mx = fmaxf(mxl, __shfl_xor(mxl, 32));
      if (!__all(mx <= mrow + 11.f)) {
        float mnew = fmaxf(mrow, mx);
        float scr = exp2f(mrow - mnew);
        mrow = mnew;
        lrow *= scr;
        if (hi == 0) scrL[wid * 32 + l5] = scr;
        float sr[16];
#pragma unroll
        for (int r = 0; r < 16; ++r)
          sr[r] = scrL[wid * 32 + (r & 3) + 8 * (r >> 2) + 4 * hi];
#pragma unroll
        for (int ct = 0; ct < 8; ++ct)
#pragma unroll
          for (int r = 0; r < 16; ++r) oa[ct][r] *= sr[r];
      }
      unsigned wp[8];
#pragma unroll
      for (int rp = 0; rp < 8; ++rp) {
        float e0 = exp2f(s[2 * rp] - mrow);
        float e1 = exp2f(s[2 * rp + 1] - mrow);
        lrow += e0 + e1;
        wp[rp] = cvtpk(e0, e1);
      }
      // ---- pack P into PV A-frags (partner exchange via shfl_xor 32) ----
      unsigned sx[8];
#pragma unroll
      for (int rp = 0; rp < 8; ++rp) sx[rp] = (unsigned)__shfl_xor((int)wp[rp], 32);
      bool hib = (hi != 0);
      u32x4 pa0u = {hib ? sx[2] : wp[0], hib ? sx[3] : wp[1],
                    hib ? wp[2] : sx[0], hib ? wp[3] : sx[1]};
      u32x4 pa1u = {hib ? sx[6] : wp[4], hib ? sx[7] : wp[5],
                    hib ? wp[6] : sx[4], hib ? wp[7] : sx[5]};
      bf16x8 pa0 = __builtin_bit_cast(bf16x8, pa0u);
      bf16x8 pa1 = __builtin_bit_cast(bf16x8, pa1u);
      // ---- PV: O[q][ch] += P x V, B=V from LDS ----
      const char* VB = smem + 65536 + buf * 32768 + h * 16384;
#pragma unroll
      for (int ct = 0; ct < 8; ++ct) {
        bf16x8 v0 = ldbf8((const unsigned short*)(VB + ct * 2048 + vbase + ko0));
        bf16x8 v1 = ldbf8((const unsigned short*)(VB + ct * 2048 + vbase + ko1));
        oa[ct] = __builtin_amdgcn_mfma_f32_32x32x16_bf16(pa0, v0, oa[ct], 0, 0, 0);
        oa[ct] = __builtin_amdgcn_mfma_f32_32x32x16_bf16(pa1, v1, oa[ct], 0, 0, 0);
      }
      __syncthreads();                     // barriers 2..65
    }
    l_all = lrow + __shfl_xor(lrow, 32);
    if (hi == 0) { cmb_m[wid * 32 + l5] = mrow; cmb_l[wid * 32 + l5] = l_all; }
  }

  // ================= epilogue =================
  __syncthreads();                         // barrier 66
  if (wid < 8) {
    float mo = cmb_m[(wid ^ 4) * 32 + l5];
    float lo = cmb_l[(wid ^ 4) * 32 + l5];
    float M = fmaxf(mrow, mo);
    float el = exp2f(mrow - M), eo = exp2f(mo - M);
    float fac = el / (l_all * el + lo * eo);
    if (hi == 0) facw[wid * 32 + l5] = fac;
  }
  if (wid < 8 && h == 0) {
    float fr[16];
#pragma unroll
    for (int r = 0; r < 16; ++r)
      fr[r] = facw[wid * 32 + (r & 3) + 8 * (r >> 2) + 4 * hi];
#pragma unroll
    for (int ct = 0; ct < 8; ++ct)
#pragma unroll
      for (int r = 0; r < 16; ++r) {
        int qr = (r & 3) + 8 * (r >> 2) + 4 * hi;
        Oacc[(qs * 32 + qr) * 256 + ct * 32 + l5] = oa[ct][r] * fr[r];
      }
  }
  __syncthreads();                         // barrier 67
  if (wid < 8 && h == 1) {
    float fr[16];
#pragma unroll
    for (int r = 0; r < 16; ++r)
      fr[r] = facw[wid * 32 + (r & 3) + 8 * (r >> 2) + 4 * hi];
#pragma unroll
    for (int ct = 0; ct < 8; ++ct)
#pragma unroll
      for (int r = 0; r < 16; ++r) {
        int qr = (r & 3) + 8 * (r >> 2) + 4 * hi;
        Oacc[(qs * 32 + qr) * 256 + ct * 32 + l5] += oa[ct][r] * fr[r];
      }
  }
  __syncthreads();                         // barrier 68
  for (int e = tid; e < 128 * 32; e += 768) {
    int row = e >> 5;
    int c8 = (e & 31) * 8;
    const float* p = Oacc + row * 256 + c8;
    u16x8 ov;
#pragma unroll
    for (int j = 0; j < 8; ++j) ov[j] = f2bf(p[j]);
    *(u16x8*)(o + ((size_t)b * HW_ + qrow0 + row) * C_ + c8) = ov;
  }
}

// ---------------- out-proj + bias + residual (W staged in LDS as bf16) -------
__global__ __launch_bounds__(256, 2) void proj_kernel(const unsigned short* __restrict__ o,
    const float* __restrict__ wp, const float* __restrict__ bp,
    const float* __restrict__ x, float* __restrict__ y) {
  int mblk = blockIdx.x, nblk = blockIdx.y;
  int n0 = nblk * 64;
  __shared__ unsigned short WL[64][264];
  int tid = threadIdx.x;
#pragma unroll
  for (int p = 0; p < 8; ++p) {
    int row = p * 8 + (tid >> 5);
    int kc0 = (tid & 31) * 8;
    *(bf16x8*)&WL[row][kc0] = cvt8(wp + (size_t)(n0 + row) * C_ + kc0);
  }
  __syncthreads();
  int wid = tid >> 6, l = tid & 63;
  int lr = l & 15, lg = l >> 4;
  int row = mblk * 64 + wid * 16 + lr;
  f32x4 acc[4] = {};
  const unsigned short* ap = o + (size_t)row * C_ + lg * 8;
#pragma unroll
  for (int kc = 0; kc < 8; ++kc) {
    bf16x8 a = ldbf8(ap + kc * 32);
#pragma unroll
    for (int j = 0; j < 4; ++j) {
      bf16x8 bb = ldbf8(&WL[j * 16 + lr][kc * 32 + lg * 8]);
      acc[j] = __builtin_amdgcn_mfma_f32_16x16x32_bf16(a, bb, acc[j], 0, 0, 0);
    }
  }
  __shared__ float lds[64][65];
#pragma unroll
  for (int j = 0; j < 4; ++j) {
    float bv_ = bp[n0 + j * 16 + lr];
#pragma unroll
    for (int r = 0; r < 4; ++r)
      lds[wid * 16 + lg * 4 + r][j * 16 + lr] = acc[j][r] + bv_;
  }
  __syncthreads();
  int bb_ = (mblk * 64) >> 12;
  int s0 = (mblk * 64) & 4095;
  int ss = tid & 63, cc0 = tid >> 6;
  for (int cc = cc0; cc < 64; cc += 4) {
    size_t idx = ((size_t)(bb_ * C_ + n0 + cc)) * HW_ + s0 + ss;
    y[idx] = x[idx] + lds[ss][cc];
  }
}

extern "C" void kernel_launch(void* const* d_in, const int* in_sizes, int n_in,
                              void* d_out, int out_size, void* d_ws, size_t ws_size,
                              hipStream_t stream) {
  const float* x     = (const float*)d_in[0];
  const float* gamma = (const float*)d_in[1];
  const float* beta  = (const float*)d_in[2];
  const float* wq    = (const float*)d_in[3];
  const float* bq    = (const float*)d_in[4];
  const float* wk    = (const float*)d_in[5];
  const float* bk    = (const float*)d_in[6];
  const float* wv    = (const float*)d_in[7];
  const float* bv    = (const float*)d_in[8];
  const float* wu    = (const float*)d_in[9];
  const float* bu    = (const float*)d_in[10];
  const float* wp    = (const float*)d_in[11];
  const float* bp    = (const float*)d_in[12];

  float* y = (float*)d_out;
  float* uout = y + (size_t)B_ * C_ * HW_;  // output 1 region; doubles as gnab scratch
                                            // before u_kernel overwrites it

  unsigned short* t  = (unsigned short*)d_ws;        // 8 MB, reused as attn output O
  unsigned short* qb = t + (size_t)M_TOT * C_;       // 8 MB
  unsigned short* kk = qb + (size_t)M_TOT * C_;      // 8 MB (pre-scaled by SCALE*u*log2e)
  unsigned short* vt = kk + (size_t)M_TOT * C_;      // 8 MB, [b][c][s]

  hipFuncSetAttribute((const void*)flash_kernel,
                      hipFuncAttributeMaxDynamicSharedMemorySize, FLASH_LDS);

  gn_stats<<<128, 256, 0, stream>>>(x, gamma, beta, uout);
  gn_apply<<<256, 256, 0, stream>>>(x, uout, t);
  u_kernel<<<4096, 256, 0, stream>>>(t, wu, bu, uout);
  qkv_kernel<<<dim3(256, 4), 256, 0, stream>>>(t, wq, wk, wv, bq, bk, bv, uout, qb, kk, vt);
  flash_kernel<<<128, 768, FLASH_LDS, stream>>>(qb, kk, vt, t);
  proj_kernel<<<dim3(256, 4), 256, 0, stream>>>(t, wp, bp, x, y);
}

// Round 14
// 188.132 us; speedup vs baseline: 2.6900x; 2.6900x over previous
//
#include <hip/hip_runtime.h>
#include <cstdint>

#define B_ 4
#define C_ 256
#define HW_ 4096
#define CPG_ 8
#define M_TOT 16384
#define SCALE 0.0625f
#define LOG2E 1.44269504088896f
#define FLASH_LDS 133120

typedef __attribute__((ext_vector_type(4))) float f32x4;
typedef __attribute__((ext_vector_type(16))) float f32x16;
typedef __attribute__((ext_vector_type(8))) unsigned short u16x8;
typedef __attribute__((ext_vector_type(4))) unsigned short u16x4;
typedef __attribute__((ext_vector_type(4))) unsigned int u32x4;
typedef __attribute__((ext_vector_type(8))) __bf16 bf16x8;

static __device__ __forceinline__ unsigned short f2bf(float f) {
  unsigned int u = __builtin_bit_cast(unsigned int, f);
  u += 0x7fffu + ((u >> 16) & 1u);
  return (unsigned short)(u >> 16);
}
static __device__ __forceinline__ float bf2f(unsigned short s) {
  return __builtin_bit_cast(float, ((unsigned int)s) << 16);
}
static __device__ __forceinline__ bf16x8 ldbf8(const unsigned short* p) {
  return __builtin_bit_cast(bf16x8, *(const u16x8*)p);
}
static __device__ __forceinline__ bf16x8 cvt8(const float* p) {
  f32x4 a = *(const f32x4*)p;
  f32x4 b = *(const f32x4*)(p + 4);
  u16x8 r;
  r[0] = f2bf(a[0]); r[1] = f2bf(a[1]); r[2] = f2bf(a[2]); r[3] = f2bf(a[3]);
  r[4] = f2bf(b[0]); r[5] = f2bf(b[1]); r[6] = f2bf(b[2]); r[7] = f2bf(b[3]);
  return __builtin_bit_cast(bf16x8, r);
}
// async global->LDS, 16B per lane; LDS dest wave-uniform base, HW adds lane*16
static __device__ __forceinline__ void gload16(const void* g, void* l) {
  __builtin_amdgcn_global_load_lds(
      (const __attribute__((address_space(1))) unsigned int*)g,
      (__attribute__((address_space(3))) unsigned int*)l, 16, 0, 0);
}
// packed f32->bf16 pair (RTNE), no builtin on gfx950
static __device__ __forceinline__ unsigned cvtpk(float lo, float hi) {
  unsigned r;
  asm("v_cvt_pk_bf16_f32 %0, %1, %2" : "=v"(r) : "v"(lo), "v"(hi));
  return r;
}

// ---------------- GroupNorm stats: per-(b,g) coefficients ----------------
__global__ __launch_bounds__(256) void gn_stats(const float* __restrict__ x,
    const float* __restrict__ gamma, const float* __restrict__ beta,
    float* __restrict__ gnab) {
  int bg = blockIdx.x;
  int b = bg >> 5, g = bg & 31;
  const float* xp = x + ((size_t)(b * C_ + g * CPG_)) * HW_;
  float s = 0.f, ss = 0.f;
  for (int i = threadIdx.x; i < CPG_ * HW_; i += 256) {
    float v = xp[i]; s += v; ss += v * v;
  }
#pragma unroll
  for (int m = 32; m; m >>= 1) { s += __shfl_xor(s, m); ss += __shfl_xor(ss, m); }
  __shared__ float red[8];
  if ((threadIdx.x & 63) == 0) { red[threadIdx.x >> 6] = s; red[4 + (threadIdx.x >> 6)] = ss; }
  __syncthreads();
  if (threadIdx.x < CPG_) {
    float S = red[0] + red[1] + red[2] + red[3];
    float SS = red[4] + red[5] + red[6] + red[7];
    float mean = S * (1.f / 32768.f);
    float var = SS * (1.f / 32768.f) - mean * mean;
    float rs = rsqrtf(var + 1e-6f);
    int c = g * CPG_ + threadIdx.x;
    float gm = gamma[c];
    gnab[b * C_ + c] = gm * rs;
    gnab[1024 + b * C_ + c] = beta[c] - mean * gm * rs;
  }
}

// ---------------- GroupNorm apply -> t bf16 [b][s][c], coalesced writes ------
__global__ __launch_bounds__(256) void gn_apply(const float* __restrict__ x,
    const float* __restrict__ gnab, unsigned short* __restrict__ t) {
  __shared__ unsigned short T[64][264];
  int blk = blockIdx.x;
  int b = blk >> 6;
  int sp0 = (blk & 63) * 64;
  int tid = threadIdx.x;
  int l = tid & 63, w = tid >> 6;
  const float* xb = x + (size_t)b * C_ * HW_;
  const float* ga = gnab + b * C_;
  const float* gb = gnab + 1024 + b * C_;
  for (int c0 = w * 64; c0 < w * 64 + 64; c0 += 8) {
    u16x8 o;
#pragma unroll
    for (int j = 0; j < 8; ++j) {
      int c = c0 + j;
      float v = xb[(size_t)c * HW_ + sp0 + l];
      o[j] = f2bf(v * ga[c] + gb[c]);
    }
    *(u16x8*)&T[l][c0] = o;
  }
  __syncthreads();
  for (int e = tid; e < 64 * 32; e += 256) {
    int row = e >> 5, c8 = (e & 31) * 8;
    *(u16x8*)(t + ((size_t)(b * HW_ + sp0 + row)) * C_ + c8) =
        *(const u16x8*)&T[row][c8];
  }
}

// ---------------- u = sigmoid(t . wu + bu), one wave per token ----------------
__global__ __launch_bounds__(256) void u_kernel(const unsigned short* __restrict__ t,
    const float* __restrict__ wu, const float* __restrict__ bu,
    float* __restrict__ uout) {
  int w = threadIdx.x >> 6, l = threadIdx.x & 63;
  int tok = blockIdx.x * 4 + w;
  u16x4 tv = *(const u16x4*)(t + (size_t)tok * C_ + l * 4);
  f32x4 wv4 = *(const f32x4*)(wu + l * 4);
  float d = bf2f(tv[0]) * wv4[0] + bf2f(tv[1]) * wv4[1] +
            bf2f(tv[2]) * wv4[2] + bf2f(tv[3]) * wv4[3];
#pragma unroll
  for (int m = 32; m; m >>= 1) d += __shfl_xor(d, m);
  if (l == 0) uout[tok] = 1.f / (1.f + __expf(-(d + bu[0])));
}

// ---------------- fused QKV projection: A in regs, 3 sequential W stages -----
// K path folds SCALE*u[row]*LOG2E so flash softmax runs in exp2 domain.
__global__ __launch_bounds__(256, 2) void qkv_kernel(const unsigned short* __restrict__ t,
    const float* __restrict__ wq, const float* __restrict__ wk, const float* __restrict__ wv,
    const float* __restrict__ bq, const float* __restrict__ bk, const float* __restrict__ bv,
    const float* __restrict__ uu,
    unsigned short* __restrict__ q, unsigned short* __restrict__ k,
    unsigned short* __restrict__ vt) {
  int mblk = blockIdx.x, nblk = blockIdx.y;
  int n0 = nblk * 64;
  __shared__ unsigned short WL[64][264];
  __shared__ float lds[64][65];
  int tid = threadIdx.x;
  int wid = tid >> 6, l = tid & 63;
  int lr = l & 15, lg = l >> 4;
  int row = mblk * 64 + wid * 16 + lr;
  bf16x8 af[8];
  const unsigned short* ap = t + (size_t)row * C_ + lg * 8;
#pragma unroll
  for (int kc = 0; kc < 8; ++kc) af[kc] = ldbf8(ap + kc * 32);
  f32x4 u4 = *(const f32x4*)(uu + mblk * 64 + wid * 16 + lg * 4);

#pragma unroll 1
  for (int w = 0; w < 3; ++w) {
    const float* W = w == 0 ? wq : (w == 1 ? wk : wv);
    const float* bias = w == 0 ? bq : (w == 1 ? bk : bv);
    if (w) __syncthreads();
#pragma unroll
    for (int p = 0; p < 8; ++p) {
      int rw = p * 8 + (tid >> 5);
      int kc0 = (tid & 31) * 8;
      *(bf16x8*)&WL[rw][kc0] = cvt8(W + (size_t)(n0 + rw) * C_ + kc0);
    }
    __syncthreads();
    f32x4 acc[4] = {};
#pragma unroll
    for (int kc = 0; kc < 8; ++kc)
#pragma unroll
      for (int j = 0; j < 4; ++j) {
        bf16x8 bb = ldbf8(&WL[j * 16 + lr][kc * 32 + lg * 8]);
        acc[j] = __builtin_amdgcn_mfma_f32_16x16x32_bf16(af[kc], bb, acc[j], 0, 0, 0);
      }
    if (w < 2) {
      unsigned short* dst = w ? k : q;
      float su[4] = {1.f, 1.f, 1.f, 1.f};
      if (w == 1) {
        su[0] = SCALE * LOG2E * u4[0]; su[1] = SCALE * LOG2E * u4[1];
        su[2] = SCALE * LOG2E * u4[2]; su[3] = SCALE * LOG2E * u4[3];
      }
#pragma unroll
      for (int j = 0; j < 4; ++j) {
        int col = n0 + j * 16 + lr;
        float bv_ = bias[col];
#pragma unroll
        for (int r = 0; r < 4; ++r)
          dst[(size_t)(mblk * 64 + wid * 16 + lg * 4 + r) * C_ + col] =
              f2bf((acc[j][r] + bv_) * su[r]);
      }
    } else {
#pragma unroll
      for (int j = 0; j < 4; ++j) {
        float bv_ = bias[n0 + j * 16 + lr];
#pragma unroll
        for (int r = 0; r < 4; ++r)
          lds[wid * 16 + lg * 4 + r][j * 16 + lr] = acc[j][r] + bv_;
      }
      __syncthreads();
      int bb_ = (mblk * 64) >> 12;
      int s0 = (mblk * 64) & 4095;
      int ss = tid & 63, cc0 = tid >> 6;
      for (int cc = cc0; cc < 64; cc += 4)
        vt[((size_t)(bb_ * C_ + n0 + cc)) * HW_ + s0 + ss] = f2bf(lds[ss][cc]);
    }
  }
}

// ---------------- flash attention v14 = exact v11/v7 body (measured best) ----
// 256 blocks x 512 threads, __launch_bounds__(512,2): 2 blocks/CU -> per SIMD
// 2 compute + 2 stager waves, 128 VGPR fits exactly. Waves 0-3 compute (zero
// vmem in loop), waves 4-7 stage K/V via global_load_lds, double-buffered.
// No setprio (regressed: starves stager issue in lockstep barrier group).
// 768-thread/128-row variants are REGISTER-INFEASIBLE (3 waves/SIMD cap ~170
// VGPR < ~230 needed -> oa spills to scratch, 3.6x slower; r12/r13).
__global__ __launch_bounds__(512, 2) void flash_kernel(const unsigned short* __restrict__ q,
    const unsigned short* __restrict__ k, const unsigned short* __restrict__ vt,
    unsigned short* __restrict__ o) {
  extern __shared__ char smem[];
  float* cmb_m = (float*)(smem + 131072);
  float* cmb_l = (float*)(smem + 131584);
  float* facw  = (float*)(smem + 132096);
  float* scrL  = (float*)(smem + 132608);

  int blk = blockIdx.x;
  int b = blk >> 6;
  int qrow0 = (blk & 63) * 64;
  int tid = threadIdx.x;
  int wid = tid >> 6, l = tid & 63;
  int l5 = l & 31, hi = l >> 5;

  const unsigned short* kb = k + (size_t)b * HW_ * C_;
  const unsigned short* vb = vt + (size_t)b * C_ * HW_;

  float mrow = -1e30f, lrow = 0.f;
  f32x16 oa[8];

  if (wid >= 4) {
    // ================= stager waves =================
    int role = wid - 4;
    int sh = role & 1;
    bool isK = role < 2;
    int w_ = l >> 2;
    int w0_ = w_ & 1, w1_ = (w_ >> 1) & 1, w2_ = (w_ >> 2) & 1, w3_ = (w_ >> 3) & 1;
    int koffb = (l & 3) * 8;
#define STG(IT, BUFN)                                                           \
    {                                                                           \
      int key0n = sh * 2048 + (IT) * 32;                                        \
      if (isK) {                                                                \
        _Pragma("unroll")                                                       \
        for (int j = 0; j < 16; ++j) {                                          \
          int key = j * 2 + hi;                                                 \
          const unsigned short* g =                                             \
              kb + (size_t)(key0n + key) * C_ + ((l5 * 8) ^ (key * 8));         \
          gload16(g, smem + (BUFN) * 32768 + sh * 16384 + j * 1024);            \
        }                                                                       \
      } else {                                                                  \
        _Pragma("unroll")                                                       \
        for (int j = 0; j < 16; ++j) {                                          \
          int j0 = j & 1;                                                       \
          int ch = (j << 4) | (w3_ << 3) | ((w2_ ^ j0) << 2) |                  \
                   ((w1_ ^ w3_) << 1) | (w0_ ^ w2_ ^ j0);                       \
          int ke = koffb ^ ((ch & 3) << 3);                                     \
          const unsigned short* g = vb + (size_t)ch * HW_ + key0n + ke;         \
          gload16(g, smem + 65536 + (BUFN) * 32768 + sh * 16384 + j * 1024);    \
        }                                                                       \
      }                                                                         \
    }
    STG(0, 0);
    __syncthreads();                       // barrier 1
    for (int it = 0; it < 64; ++it) {
      if (it + 1 < 64) STG(it + 1, (it + 1) & 1);
      __syncthreads();                     // barriers 2..65
    }
#undef STG
  } else {
    // ================= compute waves =================
    int h = wid >> 1, qs = wid & 1;
    bf16x8 qreg[16];
    {
      const unsigned short* qp =
          q + ((size_t)b * HW_ + qrow0 + qs * 32 + l5) * C_ + hi * 8;
#pragma unroll
      for (int cc = 0; cc < 16; ++cc) qreg[cc] = ldbf8(qp + cc * 16);
    }
#pragma unroll
    for (int ct = 0; ct < 8; ++ct)
#pragma unroll
      for (int r = 0; r < 16; ++r) oa[ct][r] = 0.f;
    __syncthreads();                       // barrier 1

    int kx = l5 << 4;
    int vbase = (l5 * 64) ^ ((l5 >> 2) << 6);
    int ko0 = (hi * 16) ^ ((l & 3) << 4);
    int ko1 = (32 + hi * 16) ^ ((l & 3) << 4);

    for (int it = 0; it < 64; ++it) {
      int buf = it & 1;
      // ---- QK^T swapped: S^T[key][q] (log2 units), A=K LDS, B=Q regs ----
      const char* KB = smem + buf * 32768 + h * 16384;
      f32x16 s;
#pragma unroll
      for (int r = 0; r < 16; ++r) s[r] = 0.f;
#pragma unroll
      for (int cc = 0; cc < 16; ++cc) {
        bf16x8 kf = ldbf8((const unsigned short*)(KB + l5 * 512 +
                                                  ((cc * 32 + hi * 16) ^ kx)));
        s = __builtin_amdgcn_mfma_f32_32x32x16_bf16(kf, qreg[cc], s, 0, 0, 0);
      }
      // ---- per-lane online softmax (exp2 domain, defer-max THR=11) ----
      float a0 = fmaxf(s[0], s[1]),   a1 = fmaxf(s[2], s[3]);
      float a2 = fmaxf(s[4], s[5]),   a3 = fmaxf(s[6], s[7]);
      float a4 = fmaxf(s[8], s[9]),   a5 = fmaxf(s[10], s[11]);
      float a6 = fmaxf(s[12], s[13]), a7 = fmaxf(s[14], s[15]);
      float b0 = fmaxf(fmaxf(a0, a1), fmaxf(a2, a3));
      float b1 = fmaxf(fmaxf(a4, a5), fmaxf(a6, a7));
      float mxl = fmaxf(b0, b1);
      float mx = fmaxf(mxl, __shfl_xor(mxl, 32));
      if (!__all(mx <= mrow + 11.f)) {
        float mnew = fmaxf(mrow, mx);
        float scr = exp2f(mrow - mnew);
        mrow = mnew;
        lrow *= scr;
        if (hi == 0) scrL[wid * 32 + l5] = scr;
        float sr[16];
#pragma unroll
        for (int r = 0; r < 16; ++r)
          sr[r] = scrL[wid * 32 + (r & 3) + 8 * (r >> 2) + 4 * hi];
#pragma unroll
        for (int ct = 0; ct < 8; ++ct)
#pragma unroll
          for (int r = 0; r < 16; ++r) oa[ct][r] *= sr[r];
      }
      unsigned wp[8];
#pragma unroll
      for (int rp = 0; rp < 8; ++rp) {
        float e0 = exp2f(s[2 * rp] - mrow);
        float e1 = exp2f(s[2 * rp + 1] - mrow);
        lrow += e0 + e1;
        wp[rp] = cvtpk(e0, e1);
      }
      // ---- pack P into PV A-frags (partner exchange via shfl_xor 32) ----
      unsigned sx[8];
#pragma unroll
      for (int rp = 0; rp < 8; ++rp) sx[rp] = (unsigned)__shfl_xor((int)wp[rp], 32);
      bool hib = (hi != 0);
      u32x4 pa0u = {hib ? sx[2] : wp[0], hib ? sx[3] : wp[1],
                    hib ? wp[2] : sx[0], hib ? wp[3] : sx[1]};
      u32x4 pa1u = {hib ? sx[6] : wp[4], hib ? sx[7] : wp[5],
                    hib ? wp[6] : sx[4], hib ? wp[7] : sx[5]};
      bf16x8 pa0 = __builtin_bit_cast(bf16x8, pa0u);
      bf16x8 pa1 = __builtin_bit_cast(bf16x8, pa1u);
      // ---- PV: O[q][ch] += P x V, B=V from LDS ----
      const char* VB = smem + 65536 + buf * 32768 + h * 16384;
#pragma unroll
      for (int ct = 0; ct < 8; ++ct) {
        bf16x8 v0 = ldbf8((const unsigned short*)(VB + ct * 2048 + vbase + ko0));
        bf16x8 v1 = ldbf8((const unsigned short*)(VB + ct * 2048 + vbase + ko1));
        oa[ct] = __builtin_amdgcn_mfma_f32_32x32x16_bf16(pa0, v0, oa[ct], 0, 0, 0);
        oa[ct] = __builtin_amdgcn_mfma_f32_32x32x16_bf16(pa1, v1, oa[ct], 0, 0, 0);
      }
      __syncthreads();                     // barriers 2..65
    }
  }

  // ================= epilogue =================
  float l_all = 0.f;
  if (wid < 4) {
    l_all = lrow + __shfl_xor(lrow, 32);
    if (hi == 0) { cmb_m[wid * 32 + l5] = mrow; cmb_l[wid * 32 + l5] = l_all; }
  }
  __syncthreads();                         // barrier 66
  if (wid < 4) {
    float mo = cmb_m[(wid ^ 2) * 32 + l5];
    float lo = cmb_l[(wid ^ 2) * 32 + l5];
    float M = fmaxf(mrow, mo);
    float el = exp2f(mrow - M), eo = exp2f(mo - M);
    float fac = el / (l_all * el + lo * eo);
    if (hi == 0) facw[wid * 32 + l5] = fac;
    float fr[16];
#pragma unroll
    for (int r = 0; r < 16; ++r)
      fr[r] = facw[wid * 32 + (r & 3) + 8 * (r >> 2) + 4 * hi];
    float* Ow = (float*)(smem + wid * 32768);
#pragma unroll
    for (int ct = 0; ct < 8; ++ct)
#pragma unroll
      for (int r = 0; r < 16; ++r) {
        int qr = (r & 3) + 8 * (r >> 2) + 4 * hi;
        Ow[qr * 256 + ct * 32 + l5] = oa[ct][r] * fr[r];
      }
  }
  __syncthreads();                         // barrier 67
  for (int e = tid; e < 2048; e += 512) {
    int row = e >> 5;
    int c8 = (e & 31) * 8;
    int qs_ = row >> 5, q_ = row & 31;
    const float* p0 = (const float*)(smem + qs_ * 32768) + q_ * 256 + c8;
    const float* p1 = (const float*)(smem + (2 + qs_) * 32768) + q_ * 256 + c8;
    u16x8 ov;
#pragma unroll
    for (int j = 0; j < 8; ++j) ov[j] = f2bf(p0[j] + p1[j]);
    *(u16x8*)(o + ((size_t)b * HW_ + qrow0 + row) * C_ + c8) = ov;
  }
}

// ---------------- out-proj + bias + residual (W staged in LDS as bf16) -------
__global__ __launch_bounds__(256, 2) void proj_kernel(const unsigned short* __restrict__ o,
    const float* __restrict__ wp, const float* __restrict__ bp,
    const float* __restrict__ x, float* __restrict__ y) {
  int mblk = blockIdx.x, nblk = blockIdx.y;
  int n0 = nblk * 64;
  __shared__ unsigned short WL[64][264];
  int tid = threadIdx.x;
#pragma unroll
  for (int p = 0; p < 8; ++p) {
    int row = p * 8 + (tid >> 5);
    int kc0 = (tid & 31) * 8;
    *(bf16x8*)&WL[row][kc0] = cvt8(wp + (size_t)(n0 + row) * C_ + kc0);
  }
  __syncthreads();
  int wid = tid >> 6, l = tid & 63;
  int lr = l & 15, lg = l >> 4;
  int row = mblk * 64 + wid * 16 + lr;
  f32x4 acc[4] = {};
  const unsigned short* ap = o + (size_t)row * C_ + lg * 8;
#pragma unroll
  for (int kc = 0; kc < 8; ++kc) {
    bf16x8 a = ldbf8(ap + kc * 32);
#pragma unroll
    for (int j = 0; j < 4; ++j) {
      bf16x8 bb = ldbf8(&WL[j * 16 + lr][kc * 32 + lg * 8]);
      acc[j] = __builtin_amdgcn_mfma_f32_16x16x32_bf16(a, bb, acc[j], 0, 0, 0);
    }
  }
  __shared__ float lds[64][65];
#pragma unroll
  for (int j = 0; j < 4; ++j) {
    float bv_ = bp[n0 + j * 16 + lr];
#pragma unroll
    for (int r = 0; r < 4; ++r)
      lds[wid * 16 + lg * 4 + r][j * 16 + lr] = acc[j][r] + bv_;
  }
  __syncthreads();
  int bb_ = (mblk * 64) >> 12;
  int s0 = (mblk * 64) & 4095;
  int ss = tid & 63, cc0 = tid >> 6;
  for (int cc = cc0; cc < 64; cc += 4) {
    size_t idx = ((size_t)(bb_ * C_ + n0 + cc)) * HW_ + s0 + ss;
    y[idx] = x[idx] + lds[ss][cc];
  }
}

extern "C" void kernel_launch(void* const* d_in, const int* in_sizes, int n_in,
                              void* d_out, int out_size, void* d_ws, size_t ws_size,
                              hipStream_t stream) {
  const float* x     = (const float*)d_in[0];
  const float* gamma = (const float*)d_in[1];
  const float* beta  = (const float*)d_in[2];
  const float* wq    = (const float*)d_in[3];
  const float* bq    = (const float*)d_in[4];
  const float* wk    = (const float*)d_in[5];
  const float* bk    = (const float*)d_in[6];
  const float* wv    = (const float*)d_in[7];
  const float* bv    = (const float*)d_in[8];
  const float* wu    = (const float*)d_in[9];
  const float* bu    = (const float*)d_in[10];
  const float* wp    = (const float*)d_in[11];
  const float* bp    = (const float*)d_in[12];

  float* y = (float*)d_out;
  float* uout = y + (size_t)B_ * C_ * HW_;  // output 1 region; doubles as gnab scratch
                                            // before u_kernel overwrites it

  unsigned short* t  = (unsigned short*)d_ws;        // 8 MB, reused as attn output O
  unsigned short* qb = t + (size_t)M_TOT * C_;       // 8 MB
  unsigned short* kk = qb + (size_t)M_TOT * C_;      // 8 MB (pre-scaled by SCALE*u*log2e)
  unsigned short* vt = kk + (size_t)M_TOT * C_;      // 8 MB, [b][c][s]

  hipFuncSetAttribute((const void*)flash_kernel,
                      hipFuncAttributeMaxDynamicSharedMemorySize, FLASH_LDS);

  gn_stats<<<128, 256, 0, stream>>>(x, gamma, beta, uout);
  gn_apply<<<256, 256, 0, stream>>>(x, uout, t);
  u_kernel<<<4096, 256, 0, stream>>>(t, wu, bu, uout);
  qkv_kernel<<<dim3(256, 4), 256, 0, stream>>>(t, wq, wk, wv, bq, bk, bv, uout, qb, kk, vt);
  flash_kernel<<<256, 512, FLASH_LDS, stream>>>(qb, kk, vt, t);
  proj_kernel<<<dim3(256, 4), 256, 0, stream>>>(t, wp, bp, x, y);
}

// Round 15
// 185.853 us; speedup vs baseline: 2.7230x; 1.0123x over previous
//
#include <hip/hip_runtime.h>
#include <cstdint>

#define B_ 4
#define C_ 256
#define HW_ 4096
#define CPG_ 8
#define M_TOT 16384
#define SCALE 0.0625f
#define LOG2E 1.44269504088896f
#define FLASH_LDS 133120

typedef __attribute__((ext_vector_type(4))) float f32x4;
typedef __attribute__((ext_vector_type(16))) float f32x16;
typedef __attribute__((ext_vector_type(8))) unsigned short u16x8;
typedef __attribute__((ext_vector_type(4))) unsigned short u16x4;
typedef __attribute__((ext_vector_type(4))) unsigned int u32x4;
typedef __attribute__((ext_vector_type(8))) __bf16 bf16x8;

static __device__ __forceinline__ unsigned short f2bf(float f) {
  unsigned int u = __builtin_bit_cast(unsigned int, f);
  u += 0x7fffu + ((u >> 16) & 1u);
  return (unsigned short)(u >> 16);
}
static __device__ __forceinline__ float bf2f(unsigned short s) {
  return __builtin_bit_cast(float, ((unsigned int)s) << 16);
}
static __device__ __forceinline__ bf16x8 ldbf8(const unsigned short* p) {
  return __builtin_bit_cast(bf16x8, *(const u16x8*)p);
}
static __device__ __forceinline__ bf16x8 cvt8(const float* p) {
  f32x4 a = *(const f32x4*)p;
  f32x4 b = *(const f32x4*)(p + 4);
  u16x8 r;
  r[0] = f2bf(a[0]); r[1] = f2bf(a[1]); r[2] = f2bf(a[2]); r[3] = f2bf(a[3]);
  r[4] = f2bf(b[0]); r[5] = f2bf(b[1]); r[6] = f2bf(b[2]); r[7] = f2bf(b[3]);
  return __builtin_bit_cast(bf16x8, r);
}
// async global->LDS, 16B per lane; LDS dest wave-uniform base, HW adds lane*16
static __device__ __forceinline__ void gload16(const void* g, void* l) {
  __builtin_amdgcn_global_load_lds(
      (const __attribute__((address_space(1))) unsigned int*)g,
      (__attribute__((address_space(3))) unsigned int*)l, 16, 0, 0);
}
// packed f32->bf16 pair (RTNE), no builtin on gfx950
static __device__ __forceinline__ unsigned cvtpk(float lo, float hi) {
  unsigned r;
  asm("v_cvt_pk_bf16_f32 %0, %1, %2" : "=v"(r) : "v"(lo), "v"(hi));
  return r;
}

// ---------------- GroupNorm stats: per-(b,g) coefficients -> gnab (in y) -----
__global__ __launch_bounds__(256) void gn_stats(const float* __restrict__ x,
    const float* __restrict__ gamma, const float* __restrict__ beta,
    float* __restrict__ gnab) {
  int bg = blockIdx.x;
  int b = bg >> 5, g = bg & 31;
  const float* xp = x + ((size_t)(b * C_ + g * CPG_)) * HW_;
  float s = 0.f, ss = 0.f;
  for (int i = threadIdx.x; i < CPG_ * HW_; i += 256) {
    float v = xp[i]; s += v; ss += v * v;
  }
#pragma unroll
  for (int m = 32; m; m >>= 1) { s += __shfl_xor(s, m); ss += __shfl_xor(ss, m); }
  __shared__ float red[8];
  if ((threadIdx.x & 63) == 0) { red[threadIdx.x >> 6] = s; red[4 + (threadIdx.x >> 6)] = ss; }
  __syncthreads();
  if (threadIdx.x < CPG_) {
    float S = red[0] + red[1] + red[2] + red[3];
    float SS = red[4] + red[5] + red[6] + red[7];
    float mean = S * (1.f / 32768.f);
    float var = SS * (1.f / 32768.f) - mean * mean;
    float rs = rsqrtf(var + 1e-6f);
    int c = g * CPG_ + threadIdx.x;
    float gm = gamma[c];
    gnab[b * C_ + c] = gm * rs;
    gnab[1024 + b * C_ + c] = beta[c] - mean * gm * rs;
  }
}

// ---------------- GroupNorm apply -> t bf16 [b][s][c] + FUSED u-map ----------
// Each block holds 64 tokens x 256 ch in LDS; u[tok] = sigmoid(dot(t_row,wu)
// + bu) computed from the same rounded bf16 values (u_kernel deleted).
// wu[c] is wave-uniform per j-iteration -> scalar loads, VALU hides under
// the memory-bound streaming.
__global__ __launch_bounds__(256) void gn_apply(const float* __restrict__ x,
    const float* __restrict__ gnab, const float* __restrict__ wu,
    const float* __restrict__ bu, unsigned short* __restrict__ t,
    float* __restrict__ uout) {
  __shared__ unsigned short T[64][264];
  __shared__ float up[4][64];
  int blk = blockIdx.x;
  int b = blk >> 6;
  int sp0 = (blk & 63) * 64;
  int tid = threadIdx.x;
  int l = tid & 63, w = tid >> 6;
  const float* xb = x + (size_t)b * C_ * HW_;
  const float* ga = gnab + b * C_;
  const float* gb = gnab + 1024 + b * C_;
  float dpart = 0.f;
  for (int c0 = w * 64; c0 < w * 64 + 64; c0 += 8) {
    u16x8 o;
#pragma unroll
    for (int j = 0; j < 8; ++j) {
      int c = c0 + j;
      float v = xb[(size_t)c * HW_ + sp0 + l];
      o[j] = f2bf(v * ga[c] + gb[c]);
      dpart += bf2f(o[j]) * wu[c];
    }
    *(u16x8*)&T[l][c0] = o;
  }
  up[w][l] = dpart;
  __syncthreads();
  for (int e = tid; e < 64 * 32; e += 256) {
    int row = e >> 5, c8 = (e & 31) * 8;
    *(u16x8*)(t + ((size_t)(b * HW_ + sp0 + row)) * C_ + c8) =
        *(const u16x8*)&T[row][c8];
  }
  if (tid < 64) {
    float d = up[0][tid] + up[1][tid] + up[2][tid] + up[3][tid];
    uout[b * HW_ + sp0 + tid] = 1.f / (1.f + __expf(-(d + bu[0])));
  }
}

// ---------------- fused QKV projection: A in regs, 3 sequential W stages -----
// K path folds SCALE*u[row]*LOG2E so flash softmax runs in exp2 domain.
__global__ __launch_bounds__(256, 2) void qkv_kernel(const unsigned short* __restrict__ t,
    const float* __restrict__ wq, const float* __restrict__ wk, const float* __restrict__ wv,
    const float* __restrict__ bq, const float* __restrict__ bk, const float* __restrict__ bv,
    const float* __restrict__ uu,
    unsigned short* __restrict__ q, unsigned short* __restrict__ k,
    unsigned short* __restrict__ vt) {
  int mblk = blockIdx.x, nblk = blockIdx.y;
  int n0 = nblk * 64;
  __shared__ unsigned short WL[64][264];
  __shared__ float lds[64][65];
  int tid = threadIdx.x;
  int wid = tid >> 6, l = tid & 63;
  int lr = l & 15, lg = l >> 4;
  int row = mblk * 64 + wid * 16 + lr;
  bf16x8 af[8];
  const unsigned short* ap = t + (size_t)row * C_ + lg * 8;
#pragma unroll
  for (int kc = 0; kc < 8; ++kc) af[kc] = ldbf8(ap + kc * 32);
  f32x4 u4 = *(const f32x4*)(uu + mblk * 64 + wid * 16 + lg * 4);

#pragma unroll 1
  for (int w = 0; w < 3; ++w) {
    const float* W = w == 0 ? wq : (w == 1 ? wk : wv);
    const float* bias = w == 0 ? bq : (w == 1 ? bk : bv);
    if (w) __syncthreads();
#pragma unroll
    for (int p = 0; p < 8; ++p) {
      int rw = p * 8 + (tid >> 5);
      int kc0 = (tid & 31) * 8;
      *(bf16x8*)&WL[rw][kc0] = cvt8(W + (size_t)(n0 + rw) * C_ + kc0);
    }
    __syncthreads();
    f32x4 acc[4] = {};
#pragma unroll
    for (int kc = 0; kc < 8; ++kc)
#pragma unroll
      for (int j = 0; j < 4; ++j) {
        bf16x8 bb = ldbf8(&WL[j * 16 + lr][kc * 32 + lg * 8]);
        acc[j] = __builtin_amdgcn_mfma_f32_16x16x32_bf16(af[kc], bb, acc[j], 0, 0, 0);
      }
    if (w < 2) {
      unsigned short* dst = w ? k : q;
      float su[4] = {1.f, 1.f, 1.f, 1.f};
      if (w == 1) {
        su[0] = SCALE * LOG2E * u4[0]; su[1] = SCALE * LOG2E * u4[1];
        su[2] = SCALE * LOG2E * u4[2]; su[3] = SCALE * LOG2E * u4[3];
      }
#pragma unroll
      for (int j = 0; j < 4; ++j) {
        int col = n0 + j * 16 + lr;
        float bv_ = bias[col];
#pragma unroll
        for (int r = 0; r < 4; ++r)
          dst[(size_t)(mblk * 64 + wid * 16 + lg * 4 + r) * C_ + col] =
              f2bf((acc[j][r] + bv_) * su[r]);
      }
    } else {
#pragma unroll
      for (int j = 0; j < 4; ++j) {
        float bv_ = bias[n0 + j * 16 + lr];
#pragma unroll
        for (int r = 0; r < 4; ++r)
          lds[wid * 16 + lg * 4 + r][j * 16 + lr] = acc[j][r] + bv_;
      }
      __syncthreads();
      int bb_ = (mblk * 64) >> 12;
      int s0 = (mblk * 64) & 4095;
      int ss = tid & 63, cc0 = tid >> 6;
      for (int cc = cc0; cc < 64; cc += 4)
        vt[((size_t)(bb_ * C_ + n0 + cc)) * HW_ + s0 + ss] = f2bf(lds[ss][cc]);
    }
  }
}

// ---------------- flash attention = v11/v7 body (measured best) --------------
// 256 blocks x 512 threads, 2 blocks/CU: per SIMD 2 compute + 2 stager waves,
// 128 VGPR. Waves 0-3 compute (zero vmem in loop), waves 4-7 stage K/V via
// global_load_lds, double-buffered. No setprio (regressed in this lockstep
// structure). 768-thread/128-row variants are register-infeasible (r12/r13).
__global__ __launch_bounds__(512, 2) void flash_kernel(const unsigned short* __restrict__ q,
    const unsigned short* __restrict__ k, const unsigned short* __restrict__ vt,
    unsigned short* __restrict__ o) {
  extern __shared__ char smem[];
  float* cmb_m = (float*)(smem + 131072);
  float* cmb_l = (float*)(smem + 131584);
  float* facw  = (float*)(smem + 132096);
  float* scrL  = (float*)(smem + 132608);

  int blk = blockIdx.x;
  int b = blk >> 6;
  int qrow0 = (blk & 63) * 64;
  int tid = threadIdx.x;
  int wid = tid >> 6, l = tid & 63;
  int l5 = l & 31, hi = l >> 5;

  const unsigned short* kb = k + (size_t)b * HW_ * C_;
  const unsigned short* vb = vt + (size_t)b * C_ * HW_;

  float mrow = -1e30f, lrow = 0.f;
  f32x16 oa[8];

  if (wid >= 4) {
    // ================= stager waves =================
    int role = wid - 4;
    int sh = role & 1;
    bool isK = role < 2;
    int w_ = l >> 2;
    int w0_ = w_ & 1, w1_ = (w_ >> 1) & 1, w2_ = (w_ >> 2) & 1, w3_ = (w_ >> 3) & 1;
    int koffb = (l & 3) * 8;
#define STG(IT, BUFN)                                                           \
    {                                                                           \
      int key0n = sh * 2048 + (IT) * 32;                                        \
      if (isK) {                                                                \
        _Pragma("unroll")                                                       \
        for (int j = 0; j < 16; ++j) {                                          \
          int key = j * 2 + hi;                                                 \
          const unsigned short* g =                                             \
              kb + (size_t)(key0n + key) * C_ + ((l5 * 8) ^ (key * 8));         \
          gload16(g, smem + (BUFN) * 32768 + sh * 16384 + j * 1024);            \
        }                                                                       \
      } else {                                                                  \
        _Pragma("unroll")                                                       \
        for (int j = 0; j < 16; ++j) {                                          \
          int j0 = j & 1;                                                       \
          int ch = (j << 4) | (w3_ << 3) | ((w2_ ^ j0) << 2) |                  \
                   ((w1_ ^ w3_) << 1) | (w0_ ^ w2_ ^ j0);                       \
          int ke = koffb ^ ((ch & 3) << 3);                                     \
          const unsigned short* g = vb + (size_t)ch * HW_ + key0n + ke;         \
          gload16(g, smem + 65536 + (BUFN) * 32768 + sh * 16384 + j * 1024);    \
        }                                                                       \
      }                                                                         \
    }
    STG(0, 0);
    __syncthreads();                       // barrier 1
    for (int it = 0; it < 64; ++it) {
      if (it + 1 < 64) STG(it + 1, (it + 1) & 1);
      __syncthreads();                     // barriers 2..65
    }
#undef STG
  } else {
    // ================= compute waves =================
    int h = wid >> 1, qs = wid & 1;
    bf16x8 qreg[16];
    {
      const unsigned short* qp =
          q + ((size_t)b * HW_ + qrow0 + qs * 32 + l5) * C_ + hi * 8;
#pragma unroll
      for (int cc = 0; cc < 16; ++cc) qreg[cc] = ldbf8(qp + cc * 16);
    }
#pragma unroll
    for (int ct = 0; ct < 8; ++ct)
#pragma unroll
      for (int r = 0; r < 16; ++r) oa[ct][r] = 0.f;
    __syncthreads();                       // barrier 1

    int kx = l5 << 4;
    int vbase = (l5 * 64) ^ ((l5 >> 2) << 6);
    int ko0 = (hi * 16) ^ ((l & 3) << 4);
    int ko1 = (32 + hi * 16) ^ ((l & 3) << 4);

    for (int it = 0; it < 64; ++it) {
      int buf = it & 1;
      // ---- QK^T swapped: S^T[key][q] (log2 units), A=K LDS, B=Q regs ----
      const char* KB = smem + buf * 32768 + h * 16384;
      f32x16 s;
#pragma unroll
      for (int r = 0; r < 16; ++r) s[r] = 0.f;
#pragma unroll
      for (int cc = 0; cc < 16; ++cc) {
        bf16x8 kf = ldbf8((const unsigned short*)(KB + l5 * 512 +
                                                  ((cc * 32 + hi * 16) ^ kx)));
        s = __builtin_amdgcn_mfma_f32_32x32x16_bf16(kf, qreg[cc], s, 0, 0, 0);
      }
      // ---- per-lane online softmax (exp2 domain, defer-max THR=11) ----
      float a0 = fmaxf(s[0], s[1]),   a1 = fmaxf(s[2], s[3]);
      float a2 = fmaxf(s[4], s[5]),   a3 = fmaxf(s[6], s[7]);
      float a4 = fmaxf(s[8], s[9]),   a5 = fmaxf(s[10], s[11]);
      float a6 = fmaxf(s[12], s[13]), a7 = fmaxf(s[14], s[15]);
      float b0 = fmaxf(fmaxf(a0, a1), fmaxf(a2, a3));
      float b1 = fmaxf(fmaxf(a4, a5), fmaxf(a6, a7));
      float mxl = fmaxf(b0, b1);
      float mx = fmaxf(mxl, __shfl_xor(mxl, 32));
      if (!__all(mx <= mrow + 11.f)) {
        float mnew = fmaxf(mrow, mx);
        float scr = exp2f(mrow - mnew);
        mrow = mnew;
        lrow *= scr;
        if (hi == 0) scrL[wid * 32 + l5] = scr;
        float sr[16];
#pragma unroll
        for (int r = 0; r < 16; ++r)
          sr[r] = scrL[wid * 32 + (r & 3) + 8 * (r >> 2) + 4 * hi];
#pragma unroll
        for (int ct = 0; ct < 8; ++ct)
#pragma unroll
          for (int r = 0; r < 16; ++r) oa[ct][r] *= sr[r];
      }
      unsigned wp[8];
#pragma unroll
      for (int rp = 0; rp < 8; ++rp) {
        float e0 = exp2f(s[2 * rp] - mrow);
        float e1 = exp2f(s[2 * rp + 1] - mrow);
        lrow += e0 + e1;
        wp[rp] = cvtpk(e0, e1);
      }
      // ---- pack P into PV A-frags (partner exchange via shfl_xor 32) ----
      unsigned sx[8];
#pragma unroll
      for (int rp = 0; rp < 8; ++rp) sx[rp] = (unsigned)__shfl_xor((int)wp[rp], 32);
      bool hib = (hi != 0);
      u32x4 pa0u = {hib ? sx[2] : wp[0], hib ? sx[3] : wp[1],
                    hib ? wp[2] : sx[0], hib ? wp[3] : sx[1]};
      u32x4 pa1u = {hib ? sx[6] : wp[4], hib ? sx[7] : wp[5],
                    hib ? wp[6] : sx[4], hib ? wp[7] : sx[5]};
      bf16x8 pa0 = __builtin_bit_cast(bf16x8, pa0u);
      bf16x8 pa1 = __builtin_bit_cast(bf16x8, pa1u);
      // ---- PV: O[q][ch] += P x V, B=V from LDS ----
      const char* VB = smem + 65536 + buf * 32768 + h * 16384;
#pragma unroll
      for (int ct = 0; ct < 8; ++ct) {
        bf16x8 v0 = ldbf8((const unsigned short*)(VB + ct * 2048 + vbase + ko0));
        bf16x8 v1 = ldbf8((const unsigned short*)(VB + ct * 2048 + vbase + ko1));
        oa[ct] = __builtin_amdgcn_mfma_f32_32x32x16_bf16(pa0, v0, oa[ct], 0, 0, 0);
        oa[ct] = __builtin_amdgcn_mfma_f32_32x32x16_bf16(pa1, v1, oa[ct], 0, 0, 0);
      }
      __syncthreads();                     // barriers 2..65
    }
  }

  // ================= epilogue =================
  float l_all = 0.f;
  if (wid < 4) {
    l_all = lrow + __shfl_xor(lrow, 32);
    if (hi == 0) { cmb_m[wid * 32 + l5] = mrow; cmb_l[wid * 32 + l5] = l_all; }
  }
  __syncthreads();                         // barrier 66
  if (wid < 4) {
    float mo = cmb_m[(wid ^ 2) * 32 + l5];
    float lo = cmb_l[(wid ^ 2) * 32 + l5];
    float M = fmaxf(mrow, mo);
    float el = exp2f(mrow - M), eo = exp2f(mo - M);
    float fac = el / (l_all * el + lo * eo);
    if (hi == 0) facw[wid * 32 + l5] = fac;
    float fr[16];
#pragma unroll
    for (int r = 0; r < 16; ++r)
      fr[r] = facw[wid * 32 + (r & 3) + 8 * (r >> 2) + 4 * hi];
    float* Ow = (float*)(smem + wid * 32768);
#pragma unroll
    for (int ct = 0; ct < 8; ++ct)
#pragma unroll
      for (int r = 0; r < 16; ++r) {
        int qr = (r & 3) + 8 * (r >> 2) + 4 * hi;
        Ow[qr * 256 + ct * 32 + l5] = oa[ct][r] * fr[r];
      }
  }
  __syncthreads();                         // barrier 67
  for (int e = tid; e < 2048; e += 512) {
    int row = e >> 5;
    int c8 = (e & 31) * 8;
    int qs_ = row >> 5, q_ = row & 31;
    const float* p0 = (const float*)(smem + qs_ * 32768) + q_ * 256 + c8;
    const float* p1 = (const float*)(smem + (2 + qs_) * 32768) + q_ * 256 + c8;
    u16x8 ov;
#pragma unroll
    for (int j = 0; j < 8; ++j) ov[j] = f2bf(p0[j] + p1[j]);
    *(u16x8*)(o + ((size_t)b * HW_ + qrow0 + row) * C_ + c8) = ov;
  }
}

// ---------------- out-proj + bias + residual (W staged in LDS as bf16) -------
__global__ __launch_bounds__(256, 2) void proj_kernel(const unsigned short* __restrict__ o,
    const float* __restrict__ wp, const float* __restrict__ bp,
    const float* __restrict__ x, float* __restrict__ y) {
  int mblk = blockIdx.x, nblk = blockIdx.y;
  int n0 = nblk * 64;
  __shared__ unsigned short WL[64][264];
  int tid = threadIdx.x;
#pragma unroll
  for (int p = 0; p < 8; ++p) {
    int row = p * 8 + (tid >> 5);
    int kc0 = (tid & 31) * 8;
    *(bf16x8*)&WL[row][kc0] = cvt8(wp + (size_t)(n0 + row) * C_ + kc0);
  }
  __syncthreads();
  int wid = tid >> 6, l = tid & 63;
  int lr = l & 15, lg = l >> 4;
  int row = mblk * 64 + wid * 16 + lr;
  f32x4 acc[4] = {};
  const unsigned short* ap = o + (size_t)row * C_ + lg * 8;
#pragma unroll
  for (int kc = 0; kc < 8; ++kc) {
    bf16x8 a = ldbf8(ap + kc * 32);
#pragma unroll
    for (int j = 0; j < 4; ++j) {
      bf16x8 bb = ldbf8(&WL[j * 16 + lr][kc * 32 + lg * 8]);
      acc[j] = __builtin_amdgcn_mfma_f32_16x16x32_bf16(a, bb, acc[j], 0, 0, 0);
    }
  }
  __shared__ float lds[64][65];
#pragma unroll
  for (int j = 0; j < 4; ++j) {
    float bv_ = bp[n0 + j * 16 + lr];
#pragma unroll
    for (int r = 0; r < 4; ++r)
      lds[wid * 16 + lg * 4 + r][j * 16 + lr] = acc[j][r] + bv_;
  }
  __syncthreads();
  int bb_ = (mblk * 64) >> 12;
  int s0 = (mblk * 64) & 4095;
  int ss = tid & 63, cc0 = tid >> 6;
  for (int cc = cc0; cc < 64; cc += 4) {
    size_t idx = ((size_t)(bb_ * C_ + n0 + cc)) * HW_ + s0 + ss;
    y[idx] = x[idx] + lds[ss][cc];
  }
}

extern "C" void kernel_launch(void* const* d_in, const int* in_sizes, int n_in,
                              void* d_out, int out_size, void* d_ws, size_t ws_size,
                              hipStream_t stream) {
  const float* x     = (const float*)d_in[0];
  const float* gamma = (const float*)d_in[1];
  const float* beta  = (const float*)d_in[2];
  const float* wq    = (const float*)d_in[3];
  const float* bq    = (const float*)d_in[4];
  const float* wk    = (const float*)d_in[5];
  const float* bk    = (const float*)d_in[6];
  const float* wv    = (const float*)d_in[7];
  const float* bv    = (const float*)d_in[8];
  const float* wu    = (const float*)d_in[9];
  const float* bu    = (const float*)d_in[10];
  const float* wp    = (const float*)d_in[11];
  const float* bp    = (const float*)d_in[12];

  float* y = (float*)d_out;
  float* uout = y + (size_t)B_ * C_ * HW_;  // output 1 region (u_map)
  float* gnab = y;                          // gnab scratch lives in y[0:2048];
                                            // proj fully overwrites y afterwards

  unsigned short* t  = (unsigned short*)d_ws;        // 8 MB, reused as attn output O
  unsigned short* qb = t + (size_t)M_TOT * C_;       // 8 MB
  unsigned short* kk = qb + (size_t)M_TOT * C_;      // 8 MB (pre-scaled by SCALE*u*log2e)
  unsigned short* vt = kk + (size_t)M_TOT * C_;      // 8 MB, [b][c][s]

  hipFuncSetAttribute((const void*)flash_kernel,
                      hipFuncAttributeMaxDynamicSharedMemorySize, FLASH_LDS);

  gn_stats<<<128, 256, 0, stream>>>(x, gamma, beta, gnab);
  gn_apply<<<256, 256, 0, stream>>>(x, gnab, wu, bu, t, uout);
  qkv_kernel<<<dim3(256, 4), 256, 0, stream>>>(t, wq, wk, wv, bq, bk, bv, uout, qb, kk, vt);
  flash_kernel<<<256, 512, FLASH_LDS, stream>>>(qb, kk, vt, t);
  proj_kernel<<<dim3(256, 4), 256, 0, stream>>>(t, wp, bp, x, y);
}